// Round 12
// baseline (2038.405 us; speedup 1.0000x reference)
//
#include <hip/hip_runtime.h>
#include <math.h>

// GenModel_81381040325247 — fully fused parallel-in-time, 1 dispatch.
// Grid = M*4 blocks x 1024 thr, all co-resident (cooperative launch validates;
// R8 ran this exact geometry). Per block: build LDS LUT via MLP -> sum own
// segment dW chunk -> release counter. s==0 blocks: RK4 + full-res Euler
// chain (only 4096 threads touch LDS for it — R11's 128x redundant-chain
// bank-conflict disaster avoided), publishing Z0 every 4 segments via
// threadfence+flag (R10-proven sync). Sweep blocks spin, then sweep; early
// segments sweep while the chain still runs. dW stays L3-warm sum->sweep.
// Fallback: R9's proven 3-dispatch path if cooperative launch errors.

#define NPART  4096
#define NROWS  4096
#define NSTEPS 4095
#define NH     24
#define TG     70
#define TCELLS (TG * TG)          // 4900
#define ZSCALE 5.75f              // (TG-1)/12
#define OFS    34.5f              // -(-6)*ZSCALE
#define HI     68.999f
#define DTS    (1.0f / 4095.0f)

__device__ __forceinline__ float exp2_hw(float x) {
  float r;
  asm("v_exp_f32 %0, %1" : "=v"(r) : "v"(x));
  return r;
}
__device__ __forceinline__ float tanh_hw(float x) {
  float e = exp2_hw(x * 2.8853900817779268f);   // e^{2x}
  float r = __builtin_amdgcn_rcpf(1.0f + e);
  return fmaf(-2.0f, r, 1.0f);
}

__device__ __forceinline__ void mlp_eval_fast(int idx,
    const float* __restrict__ Wf1, const float* __restrict__ bf1,
    const float* __restrict__ Wf2, const float* __restrict__ bf2,
    const float* __restrict__ Wg1, const float* __restrict__ bg1,
    const float* __restrict__ Wg2, const float* __restrict__ bg2,
    float& f0, float& f1, float& cgv)
{
  int iy = idx / TG, ix = idx - iy * TG;
  float z0 = -6.0f + ix * (12.0f / (TG - 1));
  float z1 = -6.0f + iy * (12.0f / (TG - 1));
  f0 = bf2[0]; f1 = bf2[1];
  #pragma unroll 1
  for (int h = 0; h < NH; ++h) {
    float t = tanh_hw(fmaf(z0, Wf1[h], fmaf(z1, Wf1[NH + h], bf1[h])));
    f0 = fmaf(t, Wf2[2 * h], f0);
    f1 = fmaf(t, Wf2[2 * h + 1], f1);
  }
  float gp = bg2[0];
  #pragma unroll 1
  for (int h = 0; h < NH; ++h) {
    float t = tanh_hw(fmaf(z0, Wg1[h], fmaf(z1, Wg1[NH + h], bg1[h])));
    gp = fmaf(t, Wg2[h], gp);
  }
  float sg = __builtin_amdgcn_rcpf(1.0f + exp2_hw(-gp * 1.4426950408889634f));
  cgv = 0.3f * sg * sqrtf(DTS);
}

__device__ __forceinline__ void lut_eval(const float4* __restrict__ tabs,
                                         float zx, float zy,
                                         float& F0, float& F1, float& CGv)
{
  float x = fminf(fmaxf(fmaf(zx, ZSCALE, OFS), 0.0f), HI);
  float y = fminf(fmaxf(fmaf(zy, ZSCALE, OFS), 0.0f), HI);
  float fxi = floorf(x), fyi = floorf(y);
  float fx = x - fxi, fy = y - fyi;
  int b = (int)fyi * TG + (int)fxi;
  float4 c00 = tabs[b], c10 = tabs[b + 1], c01 = tabs[b + TG], c11 = tabs[b + TG + 1];
  float u0 = fmaf(fx, c10.x - c00.x, c00.x), u1 = fmaf(fx, c11.x - c01.x, c01.x);
  F0 = fmaf(fy, u1 - u0, u0);
  u0 = fmaf(fx, c10.y - c00.y, c00.y); u1 = fmaf(fx, c11.y - c01.y, c01.y);
  F1 = fmaf(fy, u1 - u0, u0);
  u0 = fmaf(fx, c10.z - c00.z, c00.z); u1 = fmaf(fx, c11.z - c01.z, c01.z);
  CGv = fmaf(fy, u1 - u0, u0);
}

// ================= fused kernel =================
__global__ void __launch_bounds__(1024, 8)
fused_kernel(const float* __restrict__ dW, float* __restrict__ SdW,
             float* __restrict__ Z0, int* __restrict__ cnt, int* __restrict__ flags,
             const float* __restrict__ Wf1, const float* __restrict__ bf1,
             const float* __restrict__ Wf2, const float* __restrict__ bf2,
             const float* __restrict__ Wg1, const float* __restrict__ bg1,
             const float* __restrict__ Wg2, const float* __restrict__ bg2,
             const float* __restrict__ term_loc, const float* __restrict__ lts,
             const float* __restrict__ eps, float* __restrict__ out, int M)
{
  const int m   = NROWS / M;
  const int s   = blockIdx.x >> 2;
  const int pr  = blockIdx.x & 3;
  const int tix = threadIdx.x;
  const int p   = (pr << 10) | tix;
  const int nb  = gridDim.x;

  __shared__ float4 tabs[TCELLS];
  #pragma unroll 1
  for (int idx = tix; idx < TCELLS; idx += 1024) {
    float f0, f1, cgv;
    mlp_eval_fast(idx, Wf1, bf1, Wf2, bf2, Wg1, bg1, Wg2, bg2, f0, f1, cgv);
    tabs[idx] = make_float4(f0, f1, cgv, 0.0f);
  }
  __syncthreads();

  // ---- own segment sum (BW phase; whole grid) ----
  const int t0 = s * m;
  const int t1 = min(t0 + m, NSTEPS);
  {
    const float2* q = (const float2*)dW + (size_t)t0 * NPART + p;
    float2 a = make_float2(0.f, 0.f), b = make_float2(0.f, 0.f);
    int t = t0;
    #pragma unroll 1
    for (; t + 1 < t1; t += 2) {
      float2 w0 = q[0], w1 = q[NPART];
      a.x += w0.x; a.y += w0.y;
      b.x += w1.x; b.y += w1.y;
      q += 2 * NPART;
    }
    if (t < t1) { float2 w = q[0]; a.x += w.x; a.y += w.y; }
    a.x += b.x; a.y += b.y;
    *(float2*)(SdW + (size_t)s * 8192 + 2 * p) = a;
  }
  __threadfence();
  __syncthreads();
  if (tix == 0) atomicAdd(cnt, 1);

  float* zforw = out + 2 * NPART;
  float* zsamp = out + 2 * NPART + 2 * (size_t)NPART * NROWS;
  const float segdt = (float)m * DTS;
  float2 z;

  if (s == 0) {
    // ---- RK4(16) for own particle (independent of sums) ----
    const int qd = p & 3;
    const float stdv = expf(lts[qd]);
    float z0 = fmaf(stdv, eps[2 * p],     term_loc[2 * qd]);
    float z1 = fmaf(stdv, eps[2 * p + 1], term_loc[2 * qd + 1]);
    const float dt = 1.0f / 16.0f;
    #pragma unroll 1
    for (int st = 0; st < 16; ++st) {
      float K10, K11, K20, K21, K30, K31, K40, K41, cgd;
      lut_eval(tabs, z0, z1, K10, K11, cgd);
      lut_eval(tabs, fmaf(-0.5f * dt, K10, z0), fmaf(-0.5f * dt, K11, z1), K20, K21, cgd);
      lut_eval(tabs, fmaf(-0.5f * dt, K20, z0), fmaf(-0.5f * dt, K21, z1), K30, K31, cgd);
      lut_eval(tabs, fmaf(-dt, K30, z0), fmaf(-dt, K31, z1), K40, K41, cgd);
      z0 -= dt * (1.0f / 6.0f) * (K10 + 2.0f * (K20 + K30) + K40);
      z1 -= dt * (1.0f / 6.0f) * (K11 + 2.0f * (K21 + K31) + K41);
    }
    *(float2*)(out + 2 * p)   = make_float2(z0, z1);    // z_init
    *(float2*)(zforw + 2 * p) = make_float2(z0, z1);    // row 0
    if (p == 0) *(float2*)zsamp = make_float2(z0, z1);  // diag t=0
    *(float2*)(Z0 + 2 * p) = make_float2(z0, z1);
    z = make_float2(z0, z1);

    // ---- wait for all sums ----
    if (tix == 0) {
      while (__hip_atomic_load(cnt, __ATOMIC_ACQUIRE, __HIP_MEMORY_SCOPE_AGENT) < nb)
        __builtin_amdgcn_s_sleep(2);
    }
    __syncthreads();

    // ---- full-resolution Euler chain, publish every 4 segments ----
    float2 zc = z;
    #pragma unroll 1
    for (int ss = 0; ss < M - 1; ++ss) {
      float2 S = *(const float2*)(SdW + (size_t)ss * 8192 + 2 * p);
      float F0, F1, CGv;
      lut_eval(tabs, zc.x, zc.y, F0, F1, CGv);
      zc.x = fmaf(CGv, S.x, fmaf(F0, segdt, zc.x));
      zc.y = fmaf(CGv, S.y, fmaf(F1, segdt, zc.y));
      *(float2*)(Z0 + (size_t)(ss + 1) * 8192 + 2 * p) = zc;
      int r = ss + 1;
      if ((r & 3) == 0 || r == M - 1) {
        __threadfence();
        __syncthreads();
        if (tix == 0)
          __hip_atomic_store(&flags[(((r - 1) >> 2) << 2) + pr], 1,
                             __ATOMIC_RELEASE, __HIP_MEMORY_SCOPE_AGENT);
      }
    }
  } else {
    // ---- wait for own Z0 row ----
    const int g = (((s - 1) >> 2) << 2) + pr;
    if (tix == 0) {
      while (__hip_atomic_load(&flags[g], __ATOMIC_ACQUIRE, __HIP_MEMORY_SCOPE_AGENT) == 0)
        __builtin_amdgcn_s_sleep(2);
    }
    __syncthreads();
    z = *(const float2*)(Z0 + (size_t)s * 8192 + 2 * p);
  }

  // ---- fine sweep ----
  const int nst = t1 - t0;
  const float2* dwp = (const float2*)dW + (size_t)t0 * NPART + p;
  float* rowp = zforw + ((size_t)(t0 + 1) * NPART + p) * 2;

  float cfx = -1.0f, cfy = -1.0f;
  float4 c00, c10, c01, c11;
  float2 dwc = *dwp;

  #pragma unroll 1
  for (int k = 0; k < nst; ++k) {
    float2 dwn = dwc;
    if (k + 1 < nst) dwn = dwp[NPART];          // next-step prefetch
    float x = fminf(fmaxf(fmaf(z.x, ZSCALE, OFS), 0.0f), HI);
    float y = fminf(fmaxf(fmaf(z.y, ZSCALE, OFS), 0.0f), HI);
    float fxi = floorf(x), fyi = floorf(y);
    float fx = x - fxi, fy = y - fyi;
    if (fxi != cfx || fyi != cfy) {
      cfx = fxi; cfy = fyi;
      int b = (int)fyi * TG + (int)fxi;
      c00 = tabs[b]; c10 = tabs[b + 1]; c01 = tabs[b + TG]; c11 = tabs[b + TG + 1];
    }
    float u0 = fmaf(fx, c10.x - c00.x, c00.x), u1 = fmaf(fx, c11.x - c01.x, c01.x);
    float F0 = fmaf(fy, u1 - u0, u0);
    u0 = fmaf(fx, c10.y - c00.y, c00.y); u1 = fmaf(fx, c11.y - c01.y, c01.y);
    float F1 = fmaf(fy, u1 - u0, u0);
    u0 = fmaf(fx, c10.z - c00.z, c00.z); u1 = fmaf(fx, c11.z - c01.z, c01.z);
    float CG = fmaf(fy, u1 - u0, u0);
    z.x = fmaf(CG, dwc.x, fmaf(F0, DTS, z.x));
    z.y = fmaf(CG, dwc.y, fmaf(F1, DTS, z.y));
    union { float2 f; double d; } u; u.f = z;
    __builtin_nontemporal_store(u.d, (double*)rowp);
    if (t0 + k + 1 == p) *(float2*)(zsamp + 2 * p) = z;   // diagonal
    rowp += 2 * NPART;
    dwc = dwn;
    dwp += NPART;
  }
}

// ================= fallback path (R9, proven 115us) =================
__global__ void __launch_bounds__(256, 8)
sumfill_kernel(const float* __restrict__ dW, float* __restrict__ SdW,
               const float* __restrict__ Wf1, const float* __restrict__ bf1,
               const float* __restrict__ Wf2, const float* __restrict__ bf2,
               const float* __restrict__ Wg1, const float* __restrict__ bg1,
               const float* __restrict__ Wg2, const float* __restrict__ bg2,
               float4* __restrict__ tab4, int M)
{
  const int bid = blockIdx.x;
  const int nsum = M * 8;
  if (bid < nsum) {
    const int m  = NROWS / M;
    const int s  = bid >> 3;
    const int v  = ((bid & 7) << 8) + threadIdx.x;
    const int t0 = s * m;
    const int t1 = min(t0 + m, NSTEPS);
    const float4* q = (const float4*)dW + (size_t)t0 * 2048 + v;
    float4 a = make_float4(0.f, 0.f, 0.f, 0.f);
    float4 c = make_float4(0.f, 0.f, 0.f, 0.f);
    int t = t0;
    for (; t + 1 < t1; t += 2) {
      float4 w0 = q[0];
      float4 w1 = q[2048];
      a.x += w0.x; a.y += w0.y; a.z += w0.z; a.w += w0.w;
      c.x += w1.x; c.y += w1.y; c.z += w1.z; c.w += w1.w;
      q += 4096;
    }
    if (t < t1) { float4 w0 = q[0]; a.x += w0.x; a.y += w0.y; a.z += w0.z; a.w += w0.w; }
    a.x += c.x; a.y += c.y; a.z += c.z; a.w += c.w;
    ((float4*)SdW)[(size_t)s * 2048 + v] = a;
  } else {
    int idx = (bid - nsum) * 256 + threadIdx.x;
    if (idx < TCELLS) {
      float f0, f1, cgv;
      mlp_eval_fast(idx, Wf1, bf1, Wf2, bf2, Wg1, bg1, Wg2, bg2, f0, f1, cgv);
      tab4[idx] = make_float4(f0, f1, cgv, 0.0f);
    }
  }
}

__global__ void __launch_bounds__(256, 1)
chainrk4_kernel(const float4* __restrict__ tab4,
                const float* __restrict__ term_loc, const float* __restrict__ lts,
                const float* __restrict__ eps, const float* __restrict__ SdW,
                float* __restrict__ Z0, float* __restrict__ out, int M)
{
  __shared__ float4 tabs[TCELLS];
  for (int i = threadIdx.x; i < TCELLS; i += 256) tabs[i] = tab4[i];
  __syncthreads();

  const int p = blockIdx.x * 256 + threadIdx.x;
  const int q = p & 3;
  const float stdv = expf(lts[q]);
  float z0 = fmaf(stdv, eps[2 * p],     term_loc[2 * q]);
  float z1 = fmaf(stdv, eps[2 * p + 1], term_loc[2 * q + 1]);

  const float dt = 1.0f / 16.0f;
  #pragma unroll 1
  for (int st = 0; st < 16; ++st) {
    float K10, K11, K20, K21, K30, K31, K40, K41, cgd;
    lut_eval(tabs, z0, z1, K10, K11, cgd);
    lut_eval(tabs, fmaf(-0.5f * dt, K10, z0), fmaf(-0.5f * dt, K11, z1), K20, K21, cgd);
    lut_eval(tabs, fmaf(-0.5f * dt, K20, z0), fmaf(-0.5f * dt, K21, z1), K30, K31, cgd);
    lut_eval(tabs, fmaf(-dt, K30, z0), fmaf(-dt, K31, z1), K40, K41, cgd);
    z0 -= dt * (1.0f / 6.0f) * (K10 + 2.0f * (K20 + K30) + K40);
    z1 -= dt * (1.0f / 6.0f) * (K11 + 2.0f * (K21 + K31) + K41);
  }

  float* zforw = out + 2 * NPART;
  float* zsamp = out + 2 * NPART + 2 * (size_t)NPART * NROWS;
  *(float2*)(out + 2 * p)   = make_float2(z0, z1);
  *(float2*)(zforw + 2 * p) = make_float2(z0, z1);
  if (p == 0) *(float2*)zsamp = make_float2(z0, z1);
  *(float2*)(Z0 + 2 * p) = make_float2(z0, z1);

  const float segdt = (float)(NROWS / M) * DTS;
  float2 z = make_float2(z0, z1);
  float2 S = *(const float2*)(SdW + 2 * p);
  #pragma unroll 1
  for (int s = 0; s < M - 1; ++s) {
    float2 Sn = S;
    if (s + 2 < M) Sn = *(const float2*)(SdW + (size_t)(s + 1) * 8192 + 2 * p);
    float F0, F1, CGv;
    lut_eval(tabs, z.x, z.y, F0, F1, CGv);
    z.x = fmaf(CGv, S.x, fmaf(F0, segdt, z.x));
    z.y = fmaf(CGv, S.y, fmaf(F1, segdt, z.y));
    *(float2*)(Z0 + (size_t)(s + 1) * 8192 + 2 * p) = z;
    S = Sn;
  }
}

__global__ void __launch_bounds__(1024, 8)
fine_kernel(const float4* __restrict__ tab4, const float* __restrict__ dW,
            const float* __restrict__ Z0, float* __restrict__ out, int M)
{
  const int m = NROWS / M;
  const int s = blockIdx.x >> 2;
  const int p = ((blockIdx.x & 3) << 10) + threadIdx.x;
  __shared__ float4 tabs[TCELLS];
  for (int i = threadIdx.x; i < TCELLS; i += 1024) tabs[i] = tab4[i];
  __syncthreads();

  const int t0  = s * m;
  const int nst = min(m, NSTEPS - t0);
  float2 z = *(const float2*)(Z0 + (size_t)s * 8192 + 2 * p);
  const float2* dwp = (const float2*)dW + (size_t)t0 * NPART + p;
  float* rowp  = out + 2 * NPART + ((size_t)(t0 + 1) * NPART + p) * 2;
  float* zsamp = out + 2 * NPART + 2 * (size_t)NPART * NROWS;

  float cfx = -1.0f, cfy = -1.0f;
  float4 c00, c10, c01, c11;
  float2 dwc = *dwp;

  #pragma unroll 1
  for (int k = 0; k < nst; ++k) {
    float2 dwn = dwc;
    if (k + 1 < nst) dwn = dwp[NPART];
    float x = fminf(fmaxf(fmaf(z.x, ZSCALE, OFS), 0.0f), HI);
    float y = fminf(fmaxf(fmaf(z.y, ZSCALE, OFS), 0.0f), HI);
    float fxi = floorf(x), fyi = floorf(y);
    float fx = x - fxi, fy = y - fyi;
    if (fxi != cfx || fyi != cfy) {
      cfx = fxi; cfy = fyi;
      int b = (int)fyi * TG + (int)fxi;
      c00 = tabs[b]; c10 = tabs[b + 1]; c01 = tabs[b + TG]; c11 = tabs[b + TG + 1];
    }
    float u0 = fmaf(fx, c10.x - c00.x, c00.x), u1 = fmaf(fx, c11.x - c01.x, c01.x);
    float F0 = fmaf(fy, u1 - u0, u0);
    u0 = fmaf(fx, c10.y - c00.y, c00.y); u1 = fmaf(fx, c11.y - c01.y, c01.y);
    float F1 = fmaf(fy, u1 - u0, u0);
    u0 = fmaf(fx, c10.z - c00.z, c00.z); u1 = fmaf(fx, c11.z - c01.z, c01.z);
    float CG = fmaf(fy, u1 - u0, u0);
    z.x = fmaf(CG, dwc.x, fmaf(F0, DTS, z.x));
    z.y = fmaf(CG, dwc.y, fmaf(F1, DTS, z.y));
    union { float2 f; double d; } u; u.f = z;
    __builtin_nontemporal_store(u.d, (double*)rowp);
    if (t0 + k + 1 == p) *(float2*)(zsamp + 2 * p) = z;
    rowp += 2 * NPART;
    dwc = dwn;
    dwp += NPART;
  }
}

// ---------------- host ----------------
extern "C" void kernel_launch(void* const* d_in, const int* in_sizes, int n_in,
                              void* d_out, int out_size, void* d_ws, size_t ws_size,
                              hipStream_t stream) {
  // inputs: [0]=N [1]=Wf1 [2]=bf1 [3]=Wf2 [4]=bf2 [5]=Wg1 [6]=bg1 [7]=Wg2
  //         [8]=bg2 [9]=term_loc [10]=log_term_std [11]=noise_eps [12]=dW
  const float* Wf1 = (const float*)d_in[1];
  const float* bf1 = (const float*)d_in[2];
  const float* Wf2 = (const float*)d_in[3];
  const float* bf2 = (const float*)d_in[4];
  const float* Wg1 = (const float*)d_in[5];
  const float* bg1 = (const float*)d_in[6];
  const float* Wg2 = (const float*)d_in[7];
  const float* bg2 = (const float*)d_in[8];
  const float* tl  = (const float*)d_in[9];
  const float* lts = (const float*)d_in[10];
  const float* eps = (const float*)d_in[11];
  const float* dW  = (const float*)d_in[12];
  float* outp = (float*)d_out;

  const size_t tabBA = 78848;   // 4900*16 aligned up
  // layout: [tab4 (fallback only)][SdW M*32KB][Z0 M*32KB][ints 1KB]
  auto need = [&](size_t MM) { return tabBA + MM * 65536ull + 1024ull; };

  int M = 0;
  if      (ws_size >= need(128)) M = 128;
  else if (ws_size >= need(64))  M = 64;
  else if (ws_size >= need(32))  M = 32;
  if (M == 0) return;  // not expected (ws >= ~4.8MB established)

  char* ws = (char*)d_ws;
  float4* tab4 = (float4*)ws;
  float*  SdW  = (float*)(ws + tabBA);
  float*  Z0   = SdW + (size_t)M * 8192;
  int*    ints = (int*)(Z0 + (size_t)M * 8192);
  int*    cnt  = ints;
  int*    flags = ints + 4;

  hipMemsetAsync(ints, 0, 1024, stream);

  void* args[] = { (void*)&dW, (void*)&SdW, (void*)&Z0, (void*)&cnt, (void*)&flags,
                   (void*)&Wf1, (void*)&bf1, (void*)&Wf2, (void*)&bf2,
                   (void*)&Wg1, (void*)&bg1, (void*)&Wg2, (void*)&bg2,
                   (void*)&tl,  (void*)&lts, (void*)&eps, (void*)&outp, (void*)&M };
  hipError_t e = hipLaunchCooperativeKernel((const void*)fused_kernel,
                                            dim3(M * 4), dim3(1024),
                                            args, 0, stream);
  if (e != hipSuccess) {
    // fallback: R9 proven 3-dispatch path
    sumfill_kernel<<<dim3(M * 8 + 20), dim3(256), 0, stream>>>(
        dW, SdW, Wf1, bf1, Wf2, bf2, Wg1, bg1, Wg2, bg2, tab4, M);
    chainrk4_kernel<<<dim3(16), dim3(256), 0, stream>>>(
        tab4, tl, lts, eps, SdW, Z0, outp, M);
    fine_kernel<<<dim3(M * 4), dim3(1024), 0, stream>>>(tab4, dW, Z0, outp, M);
  }
}

// Round 13
// 99.054 us; speedup vs baseline: 20.5787x; 20.5787x over previous
//
#include <hip/hip_runtime.h>
#include <math.h>

// GenModel_81381040325247 — parallel-in-time, 3 dispatches, minimal serial.
//   D1 sumfill: [M*8 blocks] segment-sum dW (LDS-free, BW-bound ~21us);
//               [20 blocks] exact-MLP float4 LUT -> global tab4;
//               [16 blocks] RK4(8) z_init via EXACT MLP (LDS-free, no LUT
//               race; ~13us VALU hidden under the sum BW). Writes z_init,
//               z_forw row0, diag0, Z0start.
//   D2 superchain: 16 blocks: LDS LUT + 15 Euler super-steps over 8-segment
//               sums -> ZS rows (R10-measured math, absmax 0.0469). ~4us.
//   D3 fine:    M*4 x 1024; <=7-eval sub-chain prologue (R10's fine) then
//               m-step sweep -> z_forw + diagonal.
// R12 lesson (final): intra-kernel cross-block sync loses on this chip every
// time (R7 occupancy / R8 remat / R10 LDS regime / R12 coherence storm).
// Dispatch boundaries are cheap (~3us); keep phases in separate kernels with
// per-phase register/LDS regimes.

#define NPART  4096
#define NROWS  4096
#define NSTEPS 4095
#define NH     24
#define TG     70
#define TCELLS (TG * TG)          // 4900
#define ZSCALE 5.75f              // (TG-1)/12
#define OFS    34.5f              // -(-6)*ZSCALE
#define HI     68.999f
#define DTS    (1.0f / 4095.0f)
#define G      8                  // segments per super-segment

__device__ __forceinline__ float exp2_hw(float x) {
  float r;
  asm("v_exp_f32 %0, %1" : "=v"(r) : "v"(x));
  return r;
}
__device__ __forceinline__ float tanh_hw(float x) {
  float e = exp2_hw(x * 2.8853900817779268f);   // e^{2x}
  float r = __builtin_amdgcn_rcpf(1.0f + e);
  return fmaf(-2.0f, r, 1.0f);
}

__device__ __forceinline__ void mlp_eval_fast(int idx,
    const float* __restrict__ Wf1, const float* __restrict__ bf1,
    const float* __restrict__ Wf2, const float* __restrict__ bf2,
    const float* __restrict__ Wg1, const float* __restrict__ bg1,
    const float* __restrict__ Wg2, const float* __restrict__ bg2,
    float& f0, float& f1, float& cgv)
{
  int iy = idx / TG, ix = idx - iy * TG;
  float z0 = -6.0f + ix * (12.0f / (TG - 1));
  float z1 = -6.0f + iy * (12.0f / (TG - 1));
  f0 = bf2[0]; f1 = bf2[1];
  #pragma unroll 4
  for (int h = 0; h < NH; ++h) {
    float t = tanh_hw(fmaf(z0, Wf1[h], fmaf(z1, Wf1[NH + h], bf1[h])));
    f0 = fmaf(t, Wf2[2 * h], f0);
    f1 = fmaf(t, Wf2[2 * h + 1], f1);
  }
  float gp = bg2[0];
  #pragma unroll 4
  for (int h = 0; h < NH; ++h) {
    float t = tanh_hw(fmaf(z0, Wg1[h], fmaf(z1, Wg1[NH + h], bg1[h])));
    gp = fmaf(t, Wg2[h], gp);
  }
  float sg = __builtin_amdgcn_rcpf(1.0f + exp2_hw(-gp * 1.4426950408889634f));
  cgv = 0.3f * sg * sqrtf(DTS);
}

// exact-MLP drift (f only) — used by the RK4 blocks in D1 (no LUT, no LDS)
__device__ __forceinline__ void mlp_f(
    const float* __restrict__ Wf1, const float* __restrict__ bf1,
    const float* __restrict__ Wf2, const float* __restrict__ bf2,
    float z0, float z1, float& F0, float& F1)
{
  float f0 = bf2[0], f1 = bf2[1];
  #pragma unroll 4
  for (int h = 0; h < NH; ++h) {
    float t = tanh_hw(fmaf(z0, Wf1[h], fmaf(z1, Wf1[NH + h], bf1[h])));
    f0 = fmaf(t, Wf2[2 * h], f0);
    f1 = fmaf(t, Wf2[2 * h + 1], f1);
  }
  F0 = f0; F1 = f1;
}

__device__ __forceinline__ void lut_eval(const float4* __restrict__ tabs,
                                         float zx, float zy,
                                         float& F0, float& F1, float& CGv)
{
  float x = fminf(fmaxf(fmaf(zx, ZSCALE, OFS), 0.0f), HI);
  float y = fminf(fmaxf(fmaf(zy, ZSCALE, OFS), 0.0f), HI);
  float fxi = floorf(x), fyi = floorf(y);
  float fx = x - fxi, fy = y - fyi;
  int b = (int)fyi * TG + (int)fxi;
  float4 c00 = tabs[b], c10 = tabs[b + 1], c01 = tabs[b + TG], c11 = tabs[b + TG + 1];
  float u0 = fmaf(fx, c10.x - c00.x, c00.x), u1 = fmaf(fx, c11.x - c01.x, c01.x);
  F0 = fmaf(fy, u1 - u0, u0);
  u0 = fmaf(fx, c10.y - c00.y, c00.y); u1 = fmaf(fx, c11.y - c01.y, c01.y);
  F1 = fmaf(fy, u1 - u0, u0);
  u0 = fmaf(fx, c10.z - c00.z, c00.z); u1 = fmaf(fx, c11.z - c01.z, c01.z);
  CGv = fmaf(fy, u1 - u0, u0);
}

// ---------------- D1: segment sums + LUT fill + exact-MLP RK4 ----------------
__global__ void __launch_bounds__(256, 8)
sumfill_kernel(const float* __restrict__ dW, float* __restrict__ SdW,
               const float* __restrict__ Wf1, const float* __restrict__ bf1,
               const float* __restrict__ Wf2, const float* __restrict__ bf2,
               const float* __restrict__ Wg1, const float* __restrict__ bg1,
               const float* __restrict__ Wg2, const float* __restrict__ bg2,
               const float* __restrict__ term_loc, const float* __restrict__ lts,
               const float* __restrict__ eps,
               float4* __restrict__ tab4, float* __restrict__ Z0s,
               float* __restrict__ out, int M)
{
  const int bid = blockIdx.x;
  const int nsum = M * 8;
  if (bid < nsum) {
    // ---- segment sums ----
    const int m  = NROWS / M;
    const int s  = bid >> 3;
    const int v  = ((bid & 7) << 8) + threadIdx.x;   // float4 col 0..2047
    const int t0 = s * m;
    const int t1 = min(t0 + m, NSTEPS);
    const float4* q = (const float4*)dW + (size_t)t0 * 2048 + v;
    float4 a = make_float4(0.f, 0.f, 0.f, 0.f);
    float4 c = make_float4(0.f, 0.f, 0.f, 0.f);
    int t = t0;
    for (; t + 1 < t1; t += 2) {
      float4 w0 = q[0];
      float4 w1 = q[2048];
      a.x += w0.x; a.y += w0.y; a.z += w0.z; a.w += w0.w;
      c.x += w1.x; c.y += w1.y; c.z += w1.z; c.w += w1.w;
      q += 4096;
    }
    if (t < t1) { float4 w0 = q[0]; a.x += w0.x; a.y += w0.y; a.z += w0.z; a.w += w0.w; }
    a.x += c.x; a.y += c.y; a.z += c.z; a.w += c.w;
    ((float4*)SdW)[(size_t)s * 2048 + v] = a;
  } else if (bid < nsum + 20) {
    // ---- LUT fill ----
    int idx = (bid - nsum) * 256 + threadIdx.x;
    if (idx < TCELLS) {
      float f0, f1, cgv;
      mlp_eval_fast(idx, Wf1, bf1, Wf2, bf2, Wg1, bg1, Wg2, bg2, f0, f1, cgv);
      tab4[idx] = make_float4(f0, f1, cgv, 0.0f);
    }
  } else {
    // ---- RK4(8) z_init via exact MLP (hidden under the sum BW) ----
    const int p = (bid - nsum - 20) * 256 + threadIdx.x;   // particle 0..4095
    const int qd = p & 3;
    const float stdv = expf(lts[qd]);
    float z0 = fmaf(stdv, eps[2 * p],     term_loc[2 * qd]);
    float z1 = fmaf(stdv, eps[2 * p + 1], term_loc[2 * qd + 1]);
    const float dt = 1.0f / 8.0f;
    #pragma unroll 1
    for (int st = 0; st < 8; ++st) {
      float K10, K11, K20, K21, K30, K31, K40, K41;
      mlp_f(Wf1, bf1, Wf2, bf2, z0, z1, K10, K11);
      mlp_f(Wf1, bf1, Wf2, bf2, fmaf(-0.5f * dt, K10, z0), fmaf(-0.5f * dt, K11, z1), K20, K21);
      mlp_f(Wf1, bf1, Wf2, bf2, fmaf(-0.5f * dt, K20, z0), fmaf(-0.5f * dt, K21, z1), K30, K31);
      mlp_f(Wf1, bf1, Wf2, bf2, fmaf(-dt, K30, z0), fmaf(-dt, K31, z1), K40, K41);
      z0 -= dt * (1.0f / 6.0f) * (K10 + 2.0f * (K20 + K30) + K40);
      z1 -= dt * (1.0f / 6.0f) * (K11 + 2.0f * (K21 + K31) + K41);
    }
    float* zforw = out + 2 * NPART;
    float* zsamp = out + 2 * NPART + 2 * (size_t)NPART * NROWS;
    *(float2*)(out + 2 * p)   = make_float2(z0, z1);    // z_init
    *(float2*)(zforw + 2 * p) = make_float2(z0, z1);    // row 0
    if (p == 0) *(float2*)zsamp = make_float2(z0, z1);  // diag t=0
    *(float2*)(Z0s + 2 * p) = make_float2(z0, z1);
  }
}

// ---------------- D2: super-chain (15 serial evals) ----------------
__global__ void __launch_bounds__(256, 1)
superchain_kernel(const float4* __restrict__ tab4, const float* __restrict__ SdW,
                  const float* __restrict__ Z0s, float* __restrict__ ZS, int M)
{
  __shared__ float4 tabs[TCELLS];
  for (int i = threadIdx.x; i < TCELLS; i += 256) tabs[i] = tab4[i];
  __syncthreads();

  const int p = blockIdx.x * 256 + threadIdx.x;   // particle 0..4095
  const int m = NROWS / M;
  const int NS = M / G;
  const float sup_dt = (float)(G * m) * DTS;

  float2 z = *(const float2*)(Z0s + 2 * p);
  *(float2*)(ZS + 2 * p) = z;                     // ZS[0]
  #pragma unroll 1
  for (int S = 0; S < NS - 1; ++S) {
    float2 SS = make_float2(0.f, 0.f);
    #pragma unroll
    for (int j = 0; j < G; ++j) {
      float2 r = *(const float2*)(SdW + (size_t)(S * G + j) * 8192 + 2 * p);
      SS.x += r.x; SS.y += r.y;
    }
    float F0, F1, CGv;
    lut_eval(tabs, z.x, z.y, F0, F1, CGv);
    z.x = fmaf(CGv, SS.x, fmaf(F0, sup_dt, z.x));
    z.y = fmaf(CGv, SS.y, fmaf(F1, sup_dt, z.y));
    *(float2*)(ZS + (size_t)(S + 1) * 8192 + 2 * p) = z;
  }
}

// ---------------- D3: fine sweep (sub-chain prologue + m steps) ----------------
__global__ void __launch_bounds__(1024, 8)
fine_kernel(const float4* __restrict__ tab4, const float* __restrict__ dW,
            const float* __restrict__ SdW, const float* __restrict__ ZS,
            float* __restrict__ out, int M)
{
  const int m = NROWS / M;
  const int s = blockIdx.x >> 2;
  const int p = ((blockIdx.x & 3) << 10) + threadIdx.x;
  __shared__ float4 tabs[TCELLS];
  for (int i = threadIdx.x; i < TCELLS; i += 1024) tabs[i] = tab4[i];
  __syncthreads();

  const float segdt = (float)m * DTS;
  const int S = s >> 3, j = s & 7;

  // rebuild this segment's start from the super point (<=7 parallel evals)
  float2 z = *(const float2*)(ZS + (size_t)S * 8192 + 2 * p);
  #pragma unroll 1
  for (int jj = 0; jj < j; ++jj) {
    float2 Sr = *(const float2*)(SdW + (size_t)(S * G + jj) * 8192 + 2 * p);
    float F0, F1, CGv;
    lut_eval(tabs, z.x, z.y, F0, F1, CGv);
    z.x = fmaf(CGv, Sr.x, fmaf(F0, segdt, z.x));
    z.y = fmaf(CGv, Sr.y, fmaf(F1, segdt, z.y));
  }

  const int t0  = s * m;
  const int nst = min(m, NSTEPS - t0);
  const float2* dwp = (const float2*)dW + (size_t)t0 * NPART + p;
  float* rowp  = out + 2 * NPART + ((size_t)(t0 + 1) * NPART + p) * 2;
  float* zsamp = out + 2 * NPART + 2 * (size_t)NPART * NROWS;

  float cfx = -1.0f, cfy = -1.0f;
  float4 c00, c10, c01, c11;
  float2 dwc = *dwp;

  #pragma unroll 1
  for (int k = 0; k < nst; ++k) {
    float2 dwn = dwc;
    if (k + 1 < nst) dwn = dwp[NPART];          // next-step prefetch
    float x = fminf(fmaxf(fmaf(z.x, ZSCALE, OFS), 0.0f), HI);
    float y = fminf(fmaxf(fmaf(z.y, ZSCALE, OFS), 0.0f), HI);
    float fxi = floorf(x), fyi = floorf(y);
    float fx = x - fxi, fy = y - fyi;
    if (fxi != cfx || fyi != cfy) {
      cfx = fxi; cfy = fyi;
      int b = (int)fyi * TG + (int)fxi;
      c00 = tabs[b]; c10 = tabs[b + 1]; c01 = tabs[b + TG]; c11 = tabs[b + TG + 1];
    }
    float u0 = fmaf(fx, c10.x - c00.x, c00.x), u1 = fmaf(fx, c11.x - c01.x, c01.x);
    float F0 = fmaf(fy, u1 - u0, u0);
    u0 = fmaf(fx, c10.y - c00.y, c00.y); u1 = fmaf(fx, c11.y - c01.y, c01.y);
    float F1 = fmaf(fy, u1 - u0, u0);
    u0 = fmaf(fx, c10.z - c00.z, c00.z); u1 = fmaf(fx, c11.z - c01.z, c01.z);
    float CG = fmaf(fy, u1 - u0, u0);
    z.x = fmaf(CG, dwc.x, fmaf(F0, DTS, z.x));
    z.y = fmaf(CG, dwc.y, fmaf(F1, DTS, z.y));
    union { float2 f; double d; } u; u.f = z;
    __builtin_nontemporal_store(u.d, (double*)rowp);
    if (t0 + k + 1 == p) *(float2*)(zsamp + 2 * p) = z;   // diagonal
    rowp += 2 * NPART;
    dwc = dwn;
    dwp += NPART;
  }
}

// ---------------- serial fallback (R3, proven; ws-too-small only) ----------------
__global__ void fill_planar(const float* __restrict__ Wf1, const float* __restrict__ bf1,
                            const float* __restrict__ Wf2, const float* __restrict__ bf2,
                            const float* __restrict__ Wg1, const float* __restrict__ bg1,
                            const float* __restrict__ Wg2, const float* __restrict__ bg2,
                            float* __restrict__ tab)
{
  int idx = blockIdx.x * blockDim.x + threadIdx.x;
  if (idx >= TCELLS) return;
  float f0, f1, cg;
  mlp_eval_fast(idx, Wf1, bf1, Wf2, bf2, Wg1, bg1, Wg2, bg2, f0, f1, cg);
  tab[idx] = f0; tab[TCELLS + idx] = f1; tab[2 * TCELLS + idx] = cg;
}

__global__ void __launch_bounds__(256, 1)
sde_serial(const float* __restrict__ term_loc, const float* __restrict__ lts,
           const float* __restrict__ eps, const float* __restrict__ dW,
           const float* __restrict__ tab, float* __restrict__ out)
{
  const int tidx = threadIdx.x;
  const int tid  = blockIdx.x * 256 + tidx;
  const int pid  = tid >> 4;
  const int l    = tid & 15;
  const bool lane0 = (l == 0);

  __shared__ float tabs[3 * TCELLS];
  for (int i = tidx; i < 3 * TCELLS; i += 256) tabs[i] = tab[i];
  __syncthreads();

  const int p = pid & 3;
  const float stdv = expf(lts[p]);
  float z0 = fmaf(stdv, eps[2 * pid],     term_loc[2 * p]);
  float z1 = fmaf(stdv, eps[2 * pid + 1], term_loc[2 * p + 1]);

  auto lutF = [&](float y0, float y1, float& F0, float& F1) {
    float x = fminf(fmaxf(fmaf(y0, ZSCALE, OFS), 0.0f), HI);
    float y = fminf(fmaxf(fmaf(y1, ZSCALE, OFS), 0.0f), HI);
    float fxi = floorf(x), fyi = floorf(y);
    float fx = x - fxi, fy = y - fyi;
    int b = (int)fyi * TG + (int)fxi;
    float a00 = tabs[b], a10 = tabs[b + 1], a01 = tabs[b + TG], a11 = tabs[b + TG + 1];
    float u0 = fmaf(fx, a10 - a00, a00);
    float u1 = fmaf(fx, a11 - a01, a01);
    F0 = fmaf(fy, u1 - u0, u0);
    float b00 = tabs[TCELLS + b], b10 = tabs[TCELLS + b + 1];
    float b01 = tabs[TCELLS + b + TG], b11 = tabs[TCELLS + b + TG + 1];
    float v0 = fmaf(fx, b10 - b00, b00);
    float v1 = fmaf(fx, b11 - b01, b01);
    F1 = fmaf(fy, v1 - v0, v0);
  };

  const float dt = 1.0f / 64.0f;
  #pragma unroll 1
  for (int s = 0; s < 64; ++s) {
    float K10, K11, K20, K21, K30, K31, K40, K41;
    lutF(z0, z1, K10, K11);
    lutF(fmaf(-0.5f * dt, K10, z0), fmaf(-0.5f * dt, K11, z1), K20, K21);
    lutF(fmaf(-0.5f * dt, K20, z0), fmaf(-0.5f * dt, K21, z1), K30, K31);
    lutF(fmaf(-dt, K30, z0), fmaf(-dt, K31, z1), K40, K41);
    z0 -= dt * (1.0f / 6.0f) * (K10 + 2.0f * (K20 + K30) + K40);
    z1 -= dt * (1.0f / 6.0f) * (K11 + 2.0f * (K21 + K31) + K41);
  }

  float* zforw = out + 2 * NPART;
  float* zsamp = out + 2 * NPART + 2 * (size_t)NPART * NROWS;
  if (lane0) {
    *(float2*)(out + 2 * pid)   = make_float2(z0, z1);
    *(float2*)(zforw + 2 * pid) = make_float2(z0, z1);
    if (pid == 0) *(float2*)zsamp = make_float2(z0, z1);
  }

  const int pid_m1 = pid - 1;
  float s0 = 0.0f, s1 = 0.0f;
  float* zfp = zforw + 2 * pid + 2 * NPART;
  const float2* dwp = (const float2*)dW + pid;

  #pragma unroll 1
  for (int t = 0; t < NSTEPS; ++t) {
    float2 dw = dwp[(size_t)t * NPART];
    float x = fminf(fmaxf(fmaf(z0, ZSCALE, OFS), 0.0f), HI);
    float y = fminf(fmaxf(fmaf(z1, ZSCALE, OFS), 0.0f), HI);
    float fxi = floorf(x), fyi = floorf(y);
    float fx = x - fxi, fy = y - fyi;
    int b = (int)fyi * TG + (int)fxi;
    float a00 = tabs[b], a10 = tabs[b + 1], a01 = tabs[b + TG], a11 = tabs[b + TG + 1];
    float u0 = fmaf(fx, a10 - a00, a00);
    float u1 = fmaf(fx, a11 - a01, a01);
    float F0 = fmaf(fy, u1 - u0, u0);
    float b00 = tabs[TCELLS + b], b10 = tabs[TCELLS + b + 1];
    float b01 = tabs[TCELLS + b + TG], b11 = tabs[TCELLS + b + TG + 1];
    float v0 = fmaf(fx, b10 - b00, b00);
    float v1 = fmaf(fx, b11 - b01, b01);
    float F1 = fmaf(fy, v1 - v0, v0);
    float w00 = tabs[2 * TCELLS + b], w10 = tabs[2 * TCELLS + b + 1];
    float w01 = tabs[2 * TCELLS + b + TG], w11 = tabs[2 * TCELLS + b + TG + 1];
    float w0 = fmaf(fx, w10 - w00, w00);
    float w1 = fmaf(fx, w11 - w01, w01);
    float CG = fmaf(fy, w1 - w0, w0);
    z0 = fmaf(CG, dw.x, fmaf(F0, DTS, z0));
    z1 = fmaf(CG, dw.y, fmaf(F1, DTS, z1));
    if (lane0) *(float2*)zfp = make_float2(z0, z1);
    zfp += 2 * NPART;
    if (t == pid_m1) { s0 = z0; s1 = z1; }
  }
  if (lane0 && pid > 0) *(float2*)(zsamp + 2 * pid) = make_float2(s0, s1);
}

// ---------------- host ----------------
extern "C" void kernel_launch(void* const* d_in, const int* in_sizes, int n_in,
                              void* d_out, int out_size, void* d_ws, size_t ws_size,
                              hipStream_t stream) {
  // inputs: [0]=N [1]=Wf1 [2]=bf1 [3]=Wf2 [4]=bf2 [5]=Wg1 [6]=bg1 [7]=Wg2
  //         [8]=bg2 [9]=term_loc [10]=log_term_std [11]=noise_eps [12]=dW
  const float* Wf1 = (const float*)d_in[1];
  const float* bf1 = (const float*)d_in[2];
  const float* Wf2 = (const float*)d_in[3];
  const float* bf2 = (const float*)d_in[4];
  const float* Wg1 = (const float*)d_in[5];
  const float* bg1 = (const float*)d_in[6];
  const float* Wg2 = (const float*)d_in[7];
  const float* bg2 = (const float*)d_in[8];
  const float* tl  = (const float*)d_in[9];
  const float* lts = (const float*)d_in[10];
  const float* eps = (const float*)d_in[11];
  const float* dW  = (const float*)d_in[12];
  float* outp = (float*)d_out;

  const size_t tabBA = 78848;   // 4900*16 aligned up
  // layout: [tab4][SdW M*32KB][Z0start 32KB][ZS (M/8)*32KB]
  auto need = [&](size_t MM) {
    return tabBA + MM * 32768ull + 32768ull + (MM / G) * 32768ull;
  };

  if (ws_size >= need(32)) {
    const int M = (ws_size >= need(128)) ? 128 : ((ws_size >= need(64)) ? 64 : 32);
    char* ws = (char*)d_ws;
    float4* tab4 = (float4*)ws;
    float*  SdW  = (float*)(ws + tabBA);
    float*  Z0s  = SdW + (size_t)M * 8192;
    float*  ZS   = Z0s + 8192;
    sumfill_kernel<<<dim3(M * 8 + 20 + 16), dim3(256), 0, stream>>>(
        dW, SdW, Wf1, bf1, Wf2, bf2, Wg1, bg1, Wg2, bg2,
        tl, lts, eps, tab4, Z0s, outp, M);
    superchain_kernel<<<dim3(16), dim3(256), 0, stream>>>(tab4, SdW, Z0s, ZS, M);
    fine_kernel<<<dim3(M * 4), dim3(1024), 0, stream>>>(
        tab4, dW, SdW, ZS, outp, M);
  } else {
    // emergency serial fallback (R3 path)
    float* tab = (float*)d_ws;   // 3*TCELLS*4 = 58.8 KB
    fill_planar<<<dim3(20), dim3(256), 0, stream>>>(Wf1, bf1, Wf2, bf2,
                                                    Wg1, bg1, Wg2, bg2, tab);
    sde_serial<<<dim3(256), dim3(256), 0, stream>>>(tl, lts, eps, dW, tab, outp);
  }
}